// Round 11
// baseline (194.524 us; speedup 1.0000x reference)
//
#include <hip/hip_runtime.h>
#include <hip/hip_bf16.h>

typedef short short8 __attribute__((ext_vector_type(8)));
typedef float floatx4 __attribute__((ext_vector_type(4)));

#define NGROUP 512
#define RREG 256
#define D 512
#define ROWS 131072
#define FBAR_ELEMS (NGROUP * D)   // 262144

__device__ __forceinline__ unsigned short f2bf(float f) {
    unsigned int u = __float_as_uint(f);
    unsigned int r = (u + 0x7fffu + ((u >> 16) & 1u)) >> 16;
    return (unsigned short)r;
}
__device__ __forceinline__ float fast_tanh(float x) {
    float cx = fminf(fmaxf(x, -9.5f), 9.5f);
    float e  = __builtin_amdgcn_exp2f(cx * 2.8853900817779268f);  // e^{2cx}
    return (e - 1.f) * __builtin_amdgcn_rcpf(e + 1.f);
}

// ---- kernel 1: W1 fp32 -> bf16, K-CHUNKED PRE-SWIZZLED layout (R10 verbatim) ----
// W1c = 16 chunks of 32 KiB. Chunk kc holds k in [kc*32,kc*32+32) for all 512
// cols: element (col, kc*32+kl) at chunk byte col*64 + ((kl*2) ^ ((col&3)<<4)).
__global__ __launch_bounds__(256) void conv_w1(const float* __restrict__ W1,
                                               unsigned short* __restrict__ W1c) {
    int tid = blockIdx.x * 256 + threadIdx.x;   // 0..65535
    int P = tid * 8;                            // byte offset in 512 KiB image
    int kc = P >> 15;
    int L = P & 32767;
    int col = L >> 6;
    int q = L & 63;
    int kl = (q ^ ((col & 3) << 4)) >> 1;       // multiple of 4
    const float* src = W1 + col * 512 + kc * 32 + kl;
    float4 v = *reinterpret_cast<const float4*>(src);
    ushort4 o;
    o.x = f2bf(v.x); o.y = f2bf(v.y); o.z = f2bf(v.z); o.w = f2bf(v.w);
    *reinterpret_cast<ushort4*>((char*)W1c + P) = o;
}

// ---- kernel 2: score GEMM, K-tiled A+B double-buffer, 2 blocks/CU ----
// 2048 blocks x 512 threads (8 waves). Block = 64 rows x full N=512.
// Per K-step (BK=32): A-chunk (64x32 bf16, 4 KB) reg-staged from fp32 x
// (loads issued 2 steps early; ss accumulated; pack+ds_write late, T14),
// B-chunk (512x32 bf16, 32 KB) via global_load_lds from pre-swizzled W1c.
// One barrier per step (m97 regime). LDS ~78 KB -> 2 blocks/CU: co-resident
// block hides barrier-drain + staging latency (R10 lesson: 1 block/CU with
// full-K A left both pipes ~70% idle).
__global__ __launch_bounds__(512, 2) void score_gemm(
    const float* __restrict__ x, const unsigned short* __restrict__ W1c,
    const float* __restrict__ b1, const float* __restrict__ W2v,
    float* __restrict__ inv_norm, float* __restrict__ scores) {

    __shared__ unsigned short A_lds[2][64 * 32];    // 2 x 4 KB
    __shared__ unsigned short B_lds[2][512 * 32];   // 2 x 32 KB
    __shared__ float ss_lds[64][8];                 // 2 KB
    __shared__ float inv_s[64];
    __shared__ float scorebuf[8][64];               // 2 KB

    const int t = threadIdx.x;
    const int lane = t & 63;
    const int w = t >> 6;          // wave 0..7
    const int cl = lane & 15;
    const int hi = lane >> 4;
    const size_t row0 = (size_t)blockIdx.x * 64;

    // B stage: wave w DMAs its 64-col slice (4 KB) of chunk kc into B_lds[buf]
    auto stageB = [&](int buf, int kc) {
        const char* gb = (const char*)W1c + kc * 32768 + w * 4096 + lane * 16;
        char* lb = (char*)B_lds[buf] + w * 4096;
        #pragma unroll
        for (int i = 0; i < 4; ++i) {
            __builtin_amdgcn_global_load_lds(
                (const __attribute__((address_space(1))) void*)(gb + i * 1024),
                (__attribute__((address_space(3))) void*)(lb + i * 1024),
                16, 0, 0);
        }
    };

    // A staging geometry: thread t owns row t>>3, k-quad (t&7)*4 of each chunk.
    const int arow = t >> 3;
    const int abyte = arow * 64 + (((t & 7) * 8) ^ ((arow & 3) << 4));
    const float* xbase = x + (row0 + arow) * (size_t)D + (t & 7) * 4;

    float ssacc = 0.f;
    auto packA = [&](int buf, const float4& xv) {
        ssacc += xv.x * xv.x + xv.y * xv.y + xv.z * xv.z + xv.w * xv.w;
        ushort4 pk;
        pk.x = f2bf(xv.x); pk.y = f2bf(xv.y); pk.z = f2bf(xv.z); pk.w = f2bf(xv.w);
        *reinterpret_cast<ushort4*>((char*)A_lds[buf] + abyte) = pk;
    };

    // ---- prologue: chunks 0,1 in flight ----
    float4 xr0 = *reinterpret_cast<const float4*>(xbase);        // chunk 0
    stageB(0, 0);
    float4 xr1 = *reinterpret_cast<const float4*>(xbase + 32);   // chunk 1
    stageB(1, 1);
    packA(0, xr0);
    __syncthreads();   // A(0) visible; B(0) (and B(1)) drained

    // ---- K loop: 16 steps of 32 k ----
    floatx4 acc[4][4];
    #pragma unroll
    for (int tt = 0; tt < 4; ++tt)
        #pragma unroll
        for (int f = 0; f < 4; ++f) acc[tt][f] = floatx4{0, 0, 0, 0};

    const int bofs = (hi * 16) ^ ((cl & 3) << 4);   // shared A/B fragment swizzle

    #pragma unroll
    for (int s = 0; s < 16; ++s) {
        const int cur = s & 1, nx = cur ^ 1;

        // issue next-next x load (2-step lead hides HBM latency)
        if (s + 2 < 16) {
            float4 xv = *reinterpret_cast<const float4*>(xbase + (s + 2) * 32);
            if (s & 1) xr1 = xv; else xr0 = xv;     // set (s+2)&1 == s&1
        }
        // issue next B DMA (drained by this step's end barrier)
        if (s + 1 < 16) stageB(nx, s + 1);

        // current fragments
        short8 afr[4], bfr[4];
        #pragma unroll
        for (int tt = 0; tt < 4; ++tt)
            afr[tt] = *reinterpret_cast<const short8*>(
                (char*)A_lds[cur] + (tt * 16 + cl) * 64 + bofs);
        #pragma unroll
        for (int f = 0; f < 4; ++f)
            bfr[f] = *reinterpret_cast<const short8*>(
                (char*)B_lds[cur] + (w * 64 + f * 16 + cl) * 64 + bofs);

        #pragma unroll
        for (int tt = 0; tt < 4; ++tt)
            #pragma unroll
            for (int f = 0; f < 4; ++f)
                acc[tt][f] = __builtin_amdgcn_mfma_f32_16x16x32_bf16(
                    afr[tt], bfr[f], acc[tt][f], 0, 0, 0);

        // pack chunk s+1 (loaded one step ago) into A_lds[nx]
        if (s + 1 < 16) packA(nx, (s & 1) ? xr0 : xr1);   // set (s+1)&1

        __syncthreads();   // A(s+1)/B(s+1) ready; all waves done with [cur]
    }

    // ---- inv from accumulated ss ----
    ss_lds[arow][t & 7] = ssacc;
    __syncthreads();
    if (t < 64) {
        float ss = 0.f;
        #pragma unroll
        for (int j = 0; j < 8; ++j) ss += ss_lds[t][j];
        float inv = 1.0f / fmaxf(sqrtf(ss), 1e-12f);
        inv_s[t] = inv;
        inv_norm[row0 + t] = inv;
    }
    __syncthreads();

    // ---- epilogue: inv, tanh, w2-dot -> per-row partials (R10 verbatim) ----
    float sp[4][4];
    #pragma unroll
    for (int tt = 0; tt < 4; ++tt)
        #pragma unroll
        for (int i = 0; i < 4; ++i) sp[tt][i] = 0.f;

    float4 iv4[4];
    #pragma unroll
    for (int tt = 0; tt < 4; ++tt)
        iv4[tt] = *reinterpret_cast<const float4*>(&inv_s[tt * 16 + hi * 4]);

    #pragma unroll
    for (int f = 0; f < 4; ++f) {
        int col = w * 64 + f * 16 + cl;
        float wv = W2v[col];
        float bb = b1[col];
        #pragma unroll
        for (int tt = 0; tt < 4; ++tt) {
            sp[tt][0] += wv * fast_tanh(acc[tt][f][0] * iv4[tt].x + bb);
            sp[tt][1] += wv * fast_tanh(acc[tt][f][1] * iv4[tt].y + bb);
            sp[tt][2] += wv * fast_tanh(acc[tt][f][2] * iv4[tt].z + bb);
            sp[tt][3] += wv * fast_tanh(acc[tt][f][3] * iv4[tt].w + bb);
        }
    }

    #pragma unroll
    for (int tt = 0; tt < 4; ++tt) {
        #pragma unroll
        for (int i = 0; i < 4; ++i) {
            float v = sp[tt][i];
            v += __shfl_xor(v, 1, 64);
            v += __shfl_xor(v, 2, 64);
            v += __shfl_xor(v, 4, 64);
            v += __shfl_xor(v, 8, 64);
            if (cl == 0) scorebuf[w][tt * 16 + hi * 4 + i] = v;
        }
    }
    __syncthreads();

    if (t < 64) {
        float s = 0.f;
        #pragma unroll
        for (int q = 0; q < 8; ++q) s += scorebuf[q][t];
        scores[row0 + t] = s;
    }
}

// ---- kernel 3: softmax over r + fp32 weighted pooling (R10 verbatim) ----
__global__ __launch_bounds__(512) void softmax_pool(
    const float* __restrict__ x, const float* __restrict__ inv_norm,
    const float* __restrict__ scores, float* __restrict__ out) {

    __shared__ float F[RREG];
    __shared__ float wts[RREG];
    const int t = threadIdx.x;
    const int g = blockIdx.x;

    float s = 0.f, e = 0.f;
    if (t < RREG) { s = scores[g * RREG + t]; F[t] = s; }
    __syncthreads();
    for (int off = 128; off > 0; off >>= 1) {
        if (t < off) F[t] = fmaxf(F[t], F[t + off]);
        __syncthreads();
    }
    float mx = F[0];
    __syncthreads();
    if (t < RREG) { e = expf(s - mx); F[t] = e; }
    __syncthreads();
    for (int off = 128; off > 0; off >>= 1) {
        if (t < off) F[t] += F[t + off];
        __syncthreads();
    }
    float denom = F[0];
    if (t < RREG) {
        float al = e / denom;
        out[FBAR_ELEMS + (size_t)g * RREG + t] = al;          // output 1: alphas
        wts[t] = al * inv_norm[(size_t)g * RREG + t];
    }
    __syncthreads();

    // fbar[d=t] = sum_r (alpha_r * inv_r) * x[g,r,t]  (coalesced 2 KB/row)
    float a = 0.f;
    const float* xb = x + (size_t)g * RREG * D + t;
    #pragma unroll 16
    for (int r = 0; r < RREG; ++r) a += wts[r] * xb[(size_t)r * D];
    out[(size_t)g * D + t] = a;                               // output 0: fbar
}

extern "C" void kernel_launch(void* const* d_in, const int* in_sizes, int n_in,
                              void* d_out, int out_size, void* d_ws, size_t ws_size,
                              hipStream_t stream) {
    const float* x  = (const float*)d_in[0];
    const float* W1 = (const float*)d_in[1];
    const float* b1 = (const float*)d_in[2];
    const float* w2 = (const float*)d_in[3];
    // b2 (d_in[4]) shifts all scores uniformly -> softmax-invariant -> unused.
    float* out = (float*)d_out;

    unsigned short* W1c = (unsigned short*)d_ws;                     // 512 KiB
    float* inv_norm = (float*)((char*)d_ws + 524288);                // 512 KiB
    float* scores   = (float*)((char*)d_ws + 1048576);               // 512 KiB

    conv_w1<<<256, 256, 0, stream>>>(W1, W1c);
    score_gemm<<<ROWS / 64, 512, 0, stream>>>(x, W1c, b1, w2, inv_norm, scores);
    softmax_pool<<<NGROUP, 512, 0, stream>>>(x, inv_norm, scores, out);
}